// Round 9
// baseline (201.871 us; speedup 1.0000x reference)
//
#include <hip/hip_runtime.h>
#include <hip/hip_bf16.h>

#define N_NODES 50000
#define N_EDGES 500000
#define D_IN    128
#define D_K     384
#define D_OUT   128
#define BN_EPS  1e-5f
#define N_TASK  (2 * N_NODES)   // recv tasks then send tasks
#define NB_SCAN ((N_TASK + 1023) / 1024)   // 98
#define NBX     ((N_NODES + 255) / 256)    // 196 gemm x-blocks (256 nodes each)
#define PSTRIDE 200                        // padded partial stride (>= NBX)

typedef __bf16 bf16x8 __attribute__((ext_vector_type(8)));
typedef __bf16 bf16x4 __attribute__((ext_vector_type(4)));
typedef float  f32x4  __attribute__((ext_vector_type(4)));

// ---- workspace layout (bytes) ----
#define OFF_AGG   0ULL           // bf16 [2][50000][128] = 25,600,000
#define OFF_CNT   25600000ULL    // int  [100000]
#define OFF_OFF   26000000ULL    // int  [100001] (+pad)
#define OFF_EID   26400256ULL    // int  [1000000]       = 4,000,000
#define OFF_RKC   30400256ULL    // int  [500000]        = 2,000,000
#define OFF_RKR   32400256ULL    // int  [500000]        = 2,000,000
#define OFF_PSTAT 34400256ULL    // f32  [256][200]      =   204,800
#define OFF_SCALE 34605056ULL
#define OFF_SHIFT 34605568ULL
#define OFF_BSUM  34606080ULL    // int [98]
#define OFF_HB    34606592ULL    // bf16 [50000][128]    = 12,800,000

// ---------------- degree histogram + per-edge ranks ----------------
__global__ __launch_bounds__(256) void hist_kernel(const int* __restrict__ row,
                                                   const int* __restrict__ col,
                                                   int* __restrict__ cnt,
                                                   int* __restrict__ rank_c,
                                                   int* __restrict__ rank_r) {
    int i = blockIdx.x * blockDim.x + threadIdx.x;
    if (i < N_EDGES) {
        rank_c[i] = atomicAdd(&cnt[col[i]], 1);
        rank_r[i] = atomicAdd(&cnt[N_NODES + row[i]], 1);
    }
}

// ---------------- scan phase A: per-block sums ----------------
__global__ __launch_bounds__(1024) void partial_kernel(const int* __restrict__ cnt,
                                                       int* __restrict__ bsum) {
    __shared__ int s[1024];
    const int idx = blockIdx.x * 1024 + threadIdx.x;
    s[threadIdx.x] = (idx < N_TASK) ? cnt[idx] : 0;
    __syncthreads();
    for (int ofs = 512; ofs > 0; ofs >>= 1) {
        if (threadIdx.x < ofs) s[threadIdx.x] += s[threadIdx.x + ofs];
        __syncthreads();
    }
    if (threadIdx.x == 0) bsum[blockIdx.x] = s[0];
}

// ---------------- scan phase B: per-block scan (block offset re-derived) -------
__global__ __launch_bounds__(1024) void scanfin_kernel(const int* __restrict__ cnt,
                                                       const int* __restrict__ bsum,
                                                       int* __restrict__ off) {
    __shared__ int sb[128];
    __shared__ int s[1024];
    if (threadIdx.x < 128) sb[threadIdx.x] = (threadIdx.x < NB_SCAN) ? bsum[threadIdx.x] : 0;
    __syncthreads();
    for (int ofs = 1; ofs < 128; ofs <<= 1) {
        int t = 0;
        if (threadIdx.x < 128 && threadIdx.x >= ofs) t = sb[threadIdx.x - ofs];
        __syncthreads();
        if (threadIdx.x < 128) sb[threadIdx.x] += t;
        __syncthreads();
    }
    const int boff = (blockIdx.x == 0) ? 0 : sb[blockIdx.x - 1];

    const int idx = blockIdx.x * 1024 + threadIdx.x;
    const int v = (idx < N_TASK) ? cnt[idx] : 0;
    s[threadIdx.x] = v;
    __syncthreads();
    for (int ofs = 1; ofs < 1024; ofs <<= 1) {
        int t = (threadIdx.x >= ofs) ? s[threadIdx.x - ofs] : 0;
        __syncthreads();
        s[threadIdx.x] += t;
        __syncthreads();
    }
    const int excl = boff + s[threadIdx.x] - v;
    if (idx < N_TASK) off[idx] = excl;
    if (idx == N_TASK - 1) off[N_TASK] = excl + v;
}

// ---------------- place edge ids into CSR (no atomics: rank-based) ----------------
__global__ __launch_bounds__(256) void sid_kernel(const int* __restrict__ row,
                                                  const int* __restrict__ col,
                                                  const int* __restrict__ off,
                                                  const int* __restrict__ rank_c,
                                                  const int* __restrict__ rank_r,
                                                  int* __restrict__ eid) {
    int i = blockIdx.x * blockDim.x + threadIdx.x;
    if (i < N_EDGES) {
        eid[off[col[i]] + rank_c[i]] = i;
        eid[off[N_NODES + row[i]] + rank_r[i]] = i;
    }
}

// ---------------- gather-sum: one HALF-WAVE per (node, side) task ----------------
// 32 lanes x f32x4 = full 128-ch row per edge; 8 predicated row-loads issued per
// pass -> up to 16 outstanding loads per wave (~8 KB in flight).
__global__ __launch_bounds__(256) void gather_kernel(const float* __restrict__ edge_attr,
                                                     const int* __restrict__ off,
                                                     const int* __restrict__ eid,
                                                     __bf16* __restrict__ agg) {
    const int hl  = threadIdx.x & 31;                 // lane in half-wave
    const int hwv = (threadIdx.x >> 5) & 1;           // half index within wave
    const int wid = blockIdx.x * 8 + (threadIdx.x >> 5);
    if (wid >= N_TASK) return;
    const int beg = off[wid];
    const int end = off[wid + 1];
    const int c   = hl * 4;                           // channel base
    f32x4 acc0 = (f32x4)0.0f, acc1 = (f32x4)0.0f;

    for (int cbeg = beg; cbeg < end; cbeg += 8) {
        const int n = min(8, end - cbeg);
        const int e_reg = (hl < n) ? eid[cbeg + hl] : 0;
#pragma unroll
        for (int i = 0; i < 8; ++i) {
            const int e = __shfl(e_reg, hwv * 32 + i);
            if (i < n) {
                const f32x4 v = *(const f32x4*)(edge_attr + (size_t)e * D_IN + c);
                if (i & 1) acc1 += v; else acc0 += v;
            }
        }
    }
    acc0 += acc1;

    bf16x4 o;
#pragma unroll
    for (int q = 0; q < 4; ++q) o[q] = (__bf16)acc0[q];
    *(bf16x4*)(agg + (size_t)wid * D_IN + c) = o;
}

// ---------------- fused GEMM + bias + ReLU + BN-partials ----------------
// grid (NBX, 2): blockIdx.y = channel half (64 ch). W-half staged f32->bf16 into
// LDS (XOR-swizzled). Block = 8 waves; wave w -> nodes [bx*256 + w*32, +32).
// h stored bf16; per-channel stats exit as per-block partials (f32, exact acc).
#define ROW_B 768   // bytes per W row in LDS (384 * 2)
__global__ __launch_bounds__(512) void gemm_kernel(
    const __bf16* __restrict__ agg, const float* __restrict__ node_attr,
    const float* __restrict__ W, const float* __restrict__ bias,
    __bf16* __restrict__ hb, float* __restrict__ pstat) {
    __shared__ __align__(16) char Ws[64 * ROW_B];   // 49152 B
    __shared__ float sred[2][8][64];                // +4096 B

    const int lane = threadIdx.x & 63;
    const int w    = threadIdx.x >> 6;
    const int m    = lane & 15;   // A-row / C-col lane index
    const int g    = lane >> 4;   // k-group
    const int cy   = blockIdx.y;  // channel half

    // ---- stage W-half into LDS (f32 -> bf16), swizzled: byte ^= ((row&7)<<4) ----
    {
        const float* src = W + (size_t)cy * 64 * D_K;
#pragma unroll
        for (int i = 0; i < 6; ++i) {
            const int idx = i * 512 + threadIdx.x;        // vec16 index, 3072 total
            const int r   = idx / 48;                     // 48 vec16 per row
            const int c8  = idx % 48;                     // 8-elem group in row
            const float* p = src + (size_t)r * D_K + c8 * 8;
            f32x4 v0 = *(const f32x4*)p, v1 = *(const f32x4*)(p + 4);
            bf16x8 v;
#pragma unroll
            for (int q = 0; q < 4; ++q) { v[q] = (__bf16)v0[q]; v[q + 4] = (__bf16)v1[q]; }
            *(bf16x8*)(Ws + r * ROW_B + ((c8 * 16) ^ ((r & 7) << 4))) = v;
        }
    }
    __syncthreads();

    const int nodeA0 = blockIdx.x * 256 + w * 32 + m;
    const int nodeA1 = nodeA0 + 16;

    f32x4 acc[2][4];
#pragma unroll
    for (int i = 0; i < 2; ++i)
#pragma unroll
        for (int f = 0; f < 4; ++f) acc[i][f] = (f32x4)0.0f;

#pragma unroll
    for (int ks = 0; ks < 12; ++ks) {
        const int k0 = ks * 32;
        bf16x8 a0, a1;
#pragma unroll
        for (int i = 0; i < 8; ++i) { a0[i] = (__bf16)0.0f; a1[i] = (__bf16)0.0f; }
        if (ks < 8) {   // recv/send stored bf16
            const size_t base = (size_t)(k0 >> 7) * (N_NODES * D_IN) + (k0 & 127) + g * 8;
            if (nodeA0 < N_NODES) a0 = *(const bf16x8*)(agg + base + (size_t)nodeA0 * D_IN);
            if (nodeA1 < N_NODES) a1 = *(const bf16x8*)(agg + base + (size_t)nodeA1 * D_IN);
        } else {        // node_attr f32 -> bf16
            const size_t base = (k0 - 256) + g * 8;
            if (nodeA0 < N_NODES) {
                const float* p = node_attr + (size_t)nodeA0 * D_IN + base;
                f32x4 v0 = *(const f32x4*)p, v1 = *(const f32x4*)(p + 4);
#pragma unroll
                for (int i = 0; i < 4; ++i) { a0[i] = (__bf16)v0[i]; a0[i + 4] = (__bf16)v1[i]; }
            }
            if (nodeA1 < N_NODES) {
                const float* p = node_attr + (size_t)nodeA1 * D_IN + base;
                f32x4 v0 = *(const f32x4*)p, v1 = *(const f32x4*)(p + 4);
#pragma unroll
                for (int i = 0; i < 4; ++i) { a1[i] = (__bf16)v0[i]; a1[i + 4] = (__bf16)v1[i]; }
            }
        }
#pragma unroll
        for (int f = 0; f < 4; ++f) {
            const int r = f * 16 + m;
            const int cb = (k0 + g * 8) * 2;
            bf16x8 bfrag = *(const bf16x8*)(Ws + r * ROW_B + (cb ^ ((r & 7) << 4)));
            acc[0][f] = __builtin_amdgcn_mfma_f32_16x16x32_bf16(a0, bfrag, acc[0][f], 0, 0, 0);
            acc[1][f] = __builtin_amdgcn_mfma_f32_16x16x32_bf16(a1, bfrag, acc[1][f], 0, 0, 0);
        }
    }

    // epilogue: bias + relu + write h (bf16) + per-wave channel stats into LDS
#pragma unroll
    for (int f = 0; f < 4; ++f) {
        const int j  = cy * 64 + f * 16 + m;
        const float bj = bias[j];
        float s1 = 0.0f, s2 = 0.0f;
#pragma unroll
        for (int i = 0; i < 2; ++i) {
#pragma unroll
            for (int r = 0; r < 4; ++r) {
                const int nodeC = blockIdx.x * 256 + w * 32 + i * 16 + g * 4 + r;
                float v = acc[i][f][r] + bj;
                v = v > 0.0f ? v : 0.0f;
                if (nodeC < N_NODES) {
                    hb[(size_t)nodeC * D_OUT + j] = (__bf16)v;
                    s1 += v;
                    s2 += v * v;
                }
            }
        }
        s1 += __shfl_xor(s1, 16, 64);  s2 += __shfl_xor(s2, 16, 64);
        s1 += __shfl_xor(s1, 32, 64);  s2 += __shfl_xor(s2, 32, 64);
        if (lane < 16) { sred[0][w][f * 16 + m] = s1; sred[1][w][f * 16 + m] = s2; }
    }
    __syncthreads();
    if (threadIdx.x < 128) {
        const int s = threadIdx.x >> 6;
        const int c = threadIdx.x & 63;
        float v = 0.0f;
#pragma unroll
        for (int q = 0; q < 8; ++q) v += sred[s][q][c];
        pstat[(size_t)(s * 128 + cy * 64 + c) * PSTRIDE + blockIdx.x] = v;
    }
}

// ---------------- BN finalize: reduce partials + scale/shift ----------------
__global__ __launch_bounds__(256) void bn_finalize_kernel(
    const float* __restrict__ pstat, const float* __restrict__ gamma,
    const float* __restrict__ beta, float* __restrict__ scale, float* __restrict__ shift) {
    const int j = blockIdx.x;   // channel 0..127
    float a1 = 0.0f, a2 = 0.0f;
    for (int b = threadIdx.x; b < NBX; b += 256) {
        a1 += pstat[(size_t)j * PSTRIDE + b];
        a2 += pstat[(size_t)(128 + j) * PSTRIDE + b];
    }
#pragma unroll
    for (int ofs = 32; ofs >= 1; ofs >>= 1) {
        a1 += __shfl_xor(a1, ofs, 64);
        a2 += __shfl_xor(a2, ofs, 64);
    }
    __shared__ float w1[4], w2[4];
    if ((threadIdx.x & 63) == 0) { w1[threadIdx.x >> 6] = a1; w2[threadIdx.x >> 6] = a2; }
    __syncthreads();
    if (threadIdx.x == 0) {
        const float S1 = w1[0] + w1[1] + w1[2] + w1[3];
        const float S2 = w2[0] + w2[1] + w2[2] + w2[3];
        const float inv_n = 1.0f / (float)N_NODES;
        const float mu  = S1 * inv_n;
        const float var = S2 * inv_n - mu * mu;
        const float sc  = gamma[j] * rsqrtf(var + BN_EPS);
        scale[j] = sc;
        shift[j] = beta[j] - mu * sc;
    }
}

// ---------------- BN apply: read bf16 h, write f32 out ----------------
__global__ __launch_bounds__(256) void bn_apply_kernel(
    const __bf16* __restrict__ hb, float* __restrict__ out,
    const float* __restrict__ scale, const float* __restrict__ shift) {
    size_t i = ((size_t)blockIdx.x * blockDim.x + threadIdx.x) * 8;
    if (i >= (size_t)N_NODES * D_OUT) return;
    const int j0 = (int)(i & 127);
    bf16x8 v = *(const bf16x8*)(hb + i);
    f32x4 a, b;
#pragma unroll
    for (int q = 0; q < 4; ++q) {
        a[q] = (float)v[q]     * scale[j0 + q]     + shift[j0 + q];
        b[q] = (float)v[q + 4] * scale[j0 + 4 + q] + shift[j0 + 4 + q];
    }
    *(f32x4*)(out + i)     = a;
    *(f32x4*)(out + i + 4) = b;
}

extern "C" void kernel_launch(void* const* d_in, const int* in_sizes, int n_in,
                              void* d_out, int out_size, void* d_ws, size_t ws_size,
                              hipStream_t stream) {
    const float* edge_attr = (const float*)d_in[0];
    const float* node_attr = (const float*)d_in[1];
    const float* W         = (const float*)d_in[2];
    const float* bias      = (const float*)d_in[3];
    const float* gamma     = (const float*)d_in[4];
    const float* beta      = (const float*)d_in[5];
    const int*   row       = (const int*)d_in[6];
    const int*   col       = (const int*)d_in[7];
    float* out = (float*)d_out;

    char* ws = (char*)d_ws;
    __bf16* agg    = (__bf16*)(ws + OFF_AGG);
    int*    cnt    = (int*)(ws + OFF_CNT);
    int*    off    = (int*)(ws + OFF_OFF);
    int*    eid    = (int*)(ws + OFF_EID);
    int*    rank_c = (int*)(ws + OFF_RKC);
    int*    rank_r = (int*)(ws + OFF_RKR);
    float*  pstat  = (float*)(ws + OFF_PSTAT);
    float*  scale  = (float*)(ws + OFF_SCALE);
    float*  shift  = (float*)(ws + OFF_SHIFT);
    int*    bsum   = (int*)(ws + OFF_BSUM);
    __bf16* hb     = (__bf16*)(ws + OFF_HB);

    hipMemsetAsync(cnt, 0, N_TASK * sizeof(int), stream);

    hist_kernel<<<(N_EDGES + 255) / 256, 256, 0, stream>>>(row, col, cnt, rank_c, rank_r);
    partial_kernel<<<NB_SCAN, 1024, 0, stream>>>(cnt, bsum);
    scanfin_kernel<<<NB_SCAN, 1024, 0, stream>>>(cnt, bsum, off);
    sid_kernel<<<(N_EDGES + 255) / 256, 256, 0, stream>>>(row, col, off, rank_c, rank_r, eid);
    gather_kernel<<<(N_TASK + 7) / 8, 256, 0, stream>>>(edge_attr, off, eid, agg);
    dim3 ggrid(NBX, 2);
    gemm_kernel<<<ggrid, 512, 0, stream>>>(agg, node_attr, W, bias, hb, pstat);
    bn_finalize_kernel<<<128, 256, 0, stream>>>(pstat, gamma, beta, scale, shift);
    bn_apply_kernel<<<(N_NODES * D_OUT / 8 + 255) / 256, 256, 0, stream>>>(hb, out, scale, shift);
}